// Round 1
// baseline (736.094 us; speedup 1.0000x reference)
//
#include <hip/hip_runtime.h>
#include <math.h>

#define M_NODES 200000
#define C_DIM   256
#define E_EDGES 6400000
#define G_SEG   2048

// ---------------------------------------------------------------------------
// Kernel A: imp[i] = dot(x[i,:], W) + b      (one wave of 64 lanes per row;
// lane l holds x[row, 4l..4l+3] and W[4l..4l+3] -> float4 dot, shfl reduce)
// ---------------------------------------------------------------------------
__global__ void k_imp(const float* __restrict__ x, const float* __restrict__ W,
                      const float* __restrict__ b, float* __restrict__ imp) {
    const int lane   = threadIdx.x & 63;
    const int wave   = (blockIdx.x * blockDim.x + threadIdx.x) >> 6;
    const int nwaves = (gridDim.x * blockDim.x) >> 6;
    const float4 w4  = reinterpret_cast<const float4*>(W)[lane];
    const float bias = b[0];
    for (int row = wave; row < M_NODES; row += nwaves) {
        const float4 xv = reinterpret_cast<const float4*>(x + (size_t)row * C_DIM)[lane];
        float s = xv.x * w4.x + xv.y * w4.y + xv.z * w4.z + xv.w * w4.w;
        #pragma unroll
        for (int off = 32; off >= 1; off >>= 1)
            s += __shfl_xor(s, off, 64);
        if (lane == 0) imp[row] = s + bias;
    }
}

// ---------------------------------------------------------------------------
// Kernel B: deg[i] = # of e with edge[0][e] == i   (float histogram, exact:
// integer-valued fp32 adds are order-independent below 2^24)
// ---------------------------------------------------------------------------
__global__ void k_deg(const int* __restrict__ edge0, float* __restrict__ deg) {
    const int idx    = blockIdx.x * blockDim.x + threadIdx.x;
    const int stride = gridDim.x * blockDim.x;
    for (int e = idx; e < E_EDGES; e += stride) {
        atomicAdd(&deg[edge0[e]], 1.0f);
    }
}

// ---------------------------------------------------------------------------
// Kernel C: per-segment softmax of imp and deg, fused into one coefficient:
//   coeff[i] = softmax_seg(imp)[i] + softmax_seg(deg)[i]
// batch is sorted -> each segment g is contiguous [start,end). One wave per
// segment; boundaries via binary search; 3 shfl-reduce passes.
// ---------------------------------------------------------------------------
__global__ void k_coeff(const float* __restrict__ imp, const float* __restrict__ deg,
                        const int* __restrict__ batch, float* __restrict__ coeff) {
    const int lane = threadIdx.x & 63;
    const int g    = blockIdx.x * (blockDim.x >> 6) + (threadIdx.x >> 6);
    if (g >= G_SEG) return;

    // lower_bound(batch, g) and lower_bound(batch, g+1)
    int lo = 0, hi = M_NODES;
    while (lo < hi) { int mid = (lo + hi) >> 1; if (batch[mid] < g) lo = mid + 1; else hi = mid; }
    const int start = lo;
    hi = M_NODES;
    while (lo < hi) { int mid = (lo + hi) >> 1; if (batch[mid] < g + 1) lo = mid + 1; else hi = mid; }
    const int end = lo;
    if (start >= end) return;

    // pass 1: segment max
    float mi = -INFINITY, md = -INFINITY;
    for (int i = start + lane; i < end; i += 64) {
        mi = fmaxf(mi, imp[i]);
        md = fmaxf(md, deg[i]);
    }
    #pragma unroll
    for (int off = 32; off >= 1; off >>= 1) {
        mi = fmaxf(mi, __shfl_xor(mi, off, 64));
        md = fmaxf(md, __shfl_xor(md, off, 64));
    }
    // pass 2: sum of exp
    float si = 0.f, sd = 0.f;
    for (int i = start + lane; i < end; i += 64) {
        si += __expf(imp[i] - mi);
        sd += __expf(deg[i] - md);
    }
    #pragma unroll
    for (int off = 32; off >= 1; off >>= 1) {
        si += __shfl_xor(si, off, 64);
        sd += __shfl_xor(sd, off, 64);
    }
    const float ri = 1.0f / si, rd = 1.0f / sd;
    // pass 3: write combined coefficient
    for (int i = start + lane; i < end; i += 64) {
        coeff[i] = __expf(imp[i] - mi) * ri + __expf(deg[i] - md) * rd;
    }
}

// ---------------------------------------------------------------------------
// Kernel D: out[i,c] = coeff[i] * x[i,c]   (float4 elementwise; 64 float4/row)
// ---------------------------------------------------------------------------
__global__ void k_out(const float* __restrict__ x, const float* __restrict__ coeff,
                      float* __restrict__ out) {
    const int total4 = M_NODES * C_DIM / 4;   // 12.8M float4
    const int stride = gridDim.x * blockDim.x;
    for (int i = blockIdx.x * blockDim.x + threadIdx.x; i < total4; i += stride) {
        const float c  = coeff[i >> 6];       // 64 float4 per row of 256
        const float4 xv = reinterpret_cast<const float4*>(x)[i];
        float4 o;
        o.x = c * xv.x; o.y = c * xv.y; o.z = c * xv.z; o.w = c * xv.w;
        reinterpret_cast<float4*>(out)[i] = o;
    }
}

// ---------------------------------------------------------------------------
extern "C" void kernel_launch(void* const* d_in, const int* in_sizes, int n_in,
                              void* d_out, int out_size, void* d_ws, size_t ws_size,
                              hipStream_t stream) {
    const float* x     = (const float*)d_in[0];
    const int*   batch = (const int*)  d_in[1];
    const int*   edge  = (const int*)  d_in[2];   // edge[0] = first E entries
    const float* W     = (const float*)d_in[3];
    const float* b     = (const float*)d_in[4];
    float* out = (float*)d_out;

    float* imp   = (float*)d_ws;          // M floats
    float* deg   = imp + M_NODES;         // M floats
    float* coeff = deg + M_NODES;         // M floats

    hipMemsetAsync(deg, 0, M_NODES * sizeof(float), stream);
    k_imp  <<<2048,    256, 0, stream>>>(x, W, b, imp);
    k_deg  <<<2048,    256, 0, stream>>>(edge, deg);
    k_coeff<<<G_SEG/4, 256, 0, stream>>>(imp, deg, batch, coeff);
    k_out  <<<2048,    256, 0, stream>>>(x, coeff, out);
}

// Round 3
// 475.775 us; speedup vs baseline: 1.5471x; 1.5471x over previous
//
#include <hip/hip_runtime.h>
#include <math.h>

#define M_NODES 200000
#define C_DIM   256
#define E_EDGES 6400000
#define G_SEG   2048

#define DEG_BINS   16384        // bins per LDS chunk (64 KB of u32)
#define DEG_NCHUNK 13           // 13*16384 = 212992 >= 200000
#define DEG_BLOCK  1024         // 16 waves/block, 2 blocks/CU (128 KB LDS)
#define DEG_P      40           // edge-slice partitions (partials live in d_out)

// ---------------------------------------------------------------------------
// Kernel A: imp[i] = dot(x[i,:], W) + b      (one wave of 64 lanes per row)
// ---------------------------------------------------------------------------
__global__ void k_imp(const float* __restrict__ x, const float* __restrict__ W,
                      const float* __restrict__ b, float* __restrict__ imp) {
    const int lane   = threadIdx.x & 63;
    const int wave   = (blockIdx.x * blockDim.x + threadIdx.x) >> 6;
    const int nwaves = (gridDim.x * blockDim.x) >> 6;
    const float4 w4  = reinterpret_cast<const float4*>(W)[lane];
    const float bias = b[0];
    for (int row = wave; row < M_NODES; row += nwaves) {
        const float4 xv = reinterpret_cast<const float4*>(x + (size_t)row * C_DIM)[lane];
        float s = xv.x * w4.x + xv.y * w4.y + xv.z * w4.z + xv.w * w4.w;
        #pragma unroll
        for (int off = 32; off >= 1; off >>= 1)
            s += __shfl_xor(s, off, 64);
        if (lane == 0) imp[row] = s + bias;
    }
}

// ---------------------------------------------------------------------------
// Kernel B: degree histogram via LDS privatization, NO global atomics.
// Grid (P, NCHUNK). Block (p,c): LDS-histogram edges of slice p whose bin is
// in chunk c, then plain coalesced store of the whole chunk into partial[p]
// (hosted in d_out, which k_out fully overwrites later). Edge array (25.6 MB)
// is L3-resident after the first pass, so the 13x re-read is cheap.
// ---------------------------------------------------------------------------
__global__ __launch_bounds__(DEG_BLOCK) void k_deg_part(const int* __restrict__ edge0,
                                                        float* __restrict__ partial) {
    __shared__ unsigned h[DEG_BINS];
    const int p    = blockIdx.x;
    const int c    = blockIdx.y;
    const int base = c * DEG_BINS;
    for (int i = threadIdx.x; i < DEG_BINS; i += DEG_BLOCK) h[i] = 0u;
    __syncthreads();

    const int ngroups = E_EDGES / 4;                 // 1.6M int4 groups
    const int per     = (ngroups + DEG_P - 1) / DEG_P;
    const int g0      = p * per;
    const int g1      = min(g0 + per, ngroups);
    const int4* e4    = reinterpret_cast<const int4*>(edge0);
    for (int g = g0 + threadIdx.x; g < g1; g += DEG_BLOCK) {
        const int4 v = e4[g];
        const unsigned a  = (unsigned)(v.x - base);
        const unsigned b2 = (unsigned)(v.y - base);
        const unsigned c2 = (unsigned)(v.z - base);
        const unsigned d2 = (unsigned)(v.w - base);
        if (a  < DEG_BINS) atomicAdd(&h[a],  1u);
        if (b2 < DEG_BINS) atomicAdd(&h[b2], 1u);
        if (c2 < DEG_BINS) atomicAdd(&h[c2], 1u);
        if (d2 < DEG_BINS) atomicAdd(&h[d2], 1u);
    }
    __syncthreads();

    float* dst = partial + (size_t)p * M_NODES + base;
    const int lim = min(DEG_BINS, M_NODES - base);
    for (int i = threadIdx.x; i < lim; i += DEG_BLOCK) dst[i] = (float)h[i];
}

// Reduce P partial histograms -> deg (float4 streaming).
__global__ void k_deg_reduce(const float* __restrict__ partial, float* __restrict__ deg) {
    const int n4     = M_NODES / 4;                  // 50000
    const int stride = gridDim.x * blockDim.x;
    for (int i = blockIdx.x * blockDim.x + threadIdx.x; i < n4; i += stride) {
        float4 s = make_float4(0.f, 0.f, 0.f, 0.f);
        for (int p = 0; p < DEG_P; ++p) {
            const float4 v = reinterpret_cast<const float4*>(partial + (size_t)p * M_NODES)[i];
            s.x += v.x; s.y += v.y; s.z += v.z; s.w += v.w;
        }
        reinterpret_cast<float4*>(deg)[i] = s;
    }
}

// ---------------------------------------------------------------------------
// Kernel C: fused per-segment double softmax -> coeff[i]
// batch is sorted -> each segment is contiguous; one wave per segment.
// ---------------------------------------------------------------------------
__global__ void k_coeff(const float* __restrict__ imp, const float* __restrict__ deg,
                        const int* __restrict__ batch, float* __restrict__ coeff) {
    const int lane = threadIdx.x & 63;
    const int g    = blockIdx.x * (blockDim.x >> 6) + (threadIdx.x >> 6);
    if (g >= G_SEG) return;

    int lo = 0, hi = M_NODES;
    while (lo < hi) { int mid = (lo + hi) >> 1; if (batch[mid] < g) lo = mid + 1; else hi = mid; }
    const int start = lo;
    hi = M_NODES;
    while (lo < hi) { int mid = (lo + hi) >> 1; if (batch[mid] < g + 1) lo = mid + 1; else hi = mid; }
    const int end = lo;
    if (start >= end) return;

    float mi = -INFINITY, md = -INFINITY;
    for (int i = start + lane; i < end; i += 64) {
        mi = fmaxf(mi, imp[i]);
        md = fmaxf(md, deg[i]);
    }
    #pragma unroll
    for (int off = 32; off >= 1; off >>= 1) {
        mi = fmaxf(mi, __shfl_xor(mi, off, 64));
        md = fmaxf(md, __shfl_xor(md, off, 64));
    }
    float si = 0.f, sd = 0.f;
    for (int i = start + lane; i < end; i += 64) {
        si += __expf(imp[i] - mi);
        sd += __expf(deg[i] - md);
    }
    #pragma unroll
    for (int off = 32; off >= 1; off >>= 1) {
        si += __shfl_xor(si, off, 64);
        sd += __shfl_xor(sd, off, 64);
    }
    const float ri = 1.0f / si, rd = 1.0f / sd;
    for (int i = start + lane; i < end; i += 64) {
        coeff[i] = __expf(imp[i] - mi) * ri + __expf(deg[i] - md) * rd;
    }
}

// ---------------------------------------------------------------------------
// Kernel D: out[i,c] = coeff[i] * x[i,c]   (float4 elementwise)
// ---------------------------------------------------------------------------
__global__ void k_out(const float* __restrict__ x, const float* __restrict__ coeff,
                      float* __restrict__ out) {
    const int total4 = M_NODES * C_DIM / 4;
    const int stride = gridDim.x * blockDim.x;
    for (int i = blockIdx.x * blockDim.x + threadIdx.x; i < total4; i += stride) {
        const float c  = coeff[i >> 6];
        const float4 xv = reinterpret_cast<const float4*>(x)[i];
        float4 o;
        o.x = c * xv.x; o.y = c * xv.y; o.z = c * xv.z; o.w = c * xv.w;
        reinterpret_cast<float4*>(out)[i] = o;
    }
}

// ---------------------------------------------------------------------------
extern "C" void kernel_launch(void* const* d_in, const int* in_sizes, int n_in,
                              void* d_out, int out_size, void* d_ws, size_t ws_size,
                              hipStream_t stream) {
    const float* x     = (const float*)d_in[0];
    const int*   batch = (const int*)  d_in[1];
    const int*   edge  = (const int*)  d_in[2];   // edge[0] = first E entries
    const float* W     = (const float*)d_in[3];
    const float* b     = (const float*)d_in[4];
    float* out = (float*)d_out;

    float* imp     = (float*)d_ws;            // M floats
    float* deg     = imp + M_NODES;           // M floats
    float* coeff   = deg + M_NODES;           // M floats
    // Partials live in d_out (204.8 MB): fully overwritten by k_out afterwards.
    float* partial = out;                     // DEG_P * M floats = 32 MB

    k_imp<<<2048, 256, 0, stream>>>(x, W, b, imp);

    dim3 grid(DEG_P, DEG_NCHUNK);
    k_deg_part  <<<grid, DEG_BLOCK, 0, stream>>>(edge, partial);
    k_deg_reduce<<<512, 256, 0, stream>>>(partial, deg);

    k_coeff<<<G_SEG / 4, 256, 0, stream>>>(imp, deg, batch, coeff);
    k_out  <<<2048, 256, 0, stream>>>(x, coeff, out);
}